// Round 1
// baseline (2896.493 us; speedup 1.0000x reference)
//
#include <hip/hip_runtime.h>
#include <math.h>

#define D 512
#define W_GRP 1536
#define T_ROWS 30000
#define NCC 30        // ceil(30000/1024)
#define NRB 24        // 1536/64
#define CHUNK 1024

__device__ __forceinline__ void top5_insert(float (&v)[5], int (&ix)[5], float s, int gi) {
    if (s <= v[4]) return;
    v[4] = s; ix[4] = gi;
    #pragma unroll
    for (int q = 4; q > 0; --q) {
        if (v[q] > v[q-1]) {
            float tv = v[q]; v[q] = v[q-1]; v[q-1] = tv;
            int ti = ix[q]; ix[q] = ix[q-1]; ix[q-1] = ti;
        } else break;
    }
}

// ---------------- Kernel A: group-average + L2-normalize -> a [1536][512]
__global__ __launch_bounds__(256) void avg_norm_kernel(const float* __restrict__ x,
                                                       float* __restrict__ a) {
    const int g = blockIdx.x, tid = threadIdx.x;
    const float* base = x + (size_t)g * 64 * D;
    float s0 = 0.f, s1 = 0.f;
    for (int r = 0; r < 64; ++r) {
        s0 += base[r * D + tid];
        s1 += base[r * D + tid + 256];
    }
    s0 *= (1.f / 64.f); s1 *= (1.f / 64.f);
    float ss = s0 * s0 + s1 * s1;
    for (int off = 32; off > 0; off >>= 1) ss += __shfl_down(ss, off, 64);
    __shared__ float red[4];
    __shared__ float scale_s;
    const int lane = tid & 63, wid = tid >> 6;
    if (lane == 0) red[wid] = ss;
    __syncthreads();
    if (tid == 0) {
        float tot = red[0] + red[1] + red[2] + red[3];
        scale_s = 1.f / fmaxf(sqrtf(tot), 1e-8f);
    }
    __syncthreads();
    const float sc = scale_s;
    a[(size_t)g * D + tid] = s0 * sc;
    a[(size_t)g * D + tid + 256] = s1 * sc;
}

// ---------------- Kernel B: inverse row-norms of short_text
__global__ __launch_bounds__(256) void tnorm_kernel(const float* __restrict__ t,
                                                    float* __restrict__ invt) {
    const int wid = threadIdx.x >> 6, lane = threadIdx.x & 63;
    const int row = blockIdx.x * 4 + wid;
    if (row >= T_ROWS) return;
    const float* p = t + (size_t)row * D;
    float ss = 0.f;
    #pragma unroll
    for (int m = 0; m < 8; ++m) { float v = p[lane + m * 64]; ss += v * v; }
    for (int off = 32; off > 0; off >>= 1) ss += __shfl_down(ss, off, 64);
    if (lane == 0) invt[row] = 1.f / fmaxf(sqrtf(ss), 1e-8f);
}

// ---------------- Kernel C: scores (a . t) * invt + fused per-chunk top-5
union SMemC {
    struct { float aT[64][68]; float tT[64][68]; } s;   // 34.8 KB
    struct { float mv[64 * 16 * 5]; int mi[64 * 16 * 5]; } m; // 40.96 KB
};

__global__ __launch_bounds__(256) void score_topk_kernel(
        const float* __restrict__ a, const float* __restrict__ t,
        const float* __restrict__ invt, float* __restrict__ cand_val,
        int* __restrict__ cand_idx) {
    __shared__ SMemC sm;
    const int tid = threadIdx.x;
    const int tx = tid & 15, ty = tid >> 4;
    const int cc = blockIdx.x, rb = blockIdx.y;
    const int r0 = ty * 4, c0 = tx * 4;

    float tv[4][5]; int tix[4][5];
    #pragma unroll
    for (int i = 0; i < 4; ++i)
        #pragma unroll
        for (int s = 0; s < 5; ++s) { tv[i][s] = -INFINITY; tix[i][s] = 0; }

    for (int ct = 0; ct < 16; ++ct) {
        const int colbase = cc * CHUNK + ct * 64;
        if (colbase >= T_ROWS) break;
        float acc[4][4];
        #pragma unroll
        for (int i = 0; i < 4; ++i)
            #pragma unroll
            for (int j = 0; j < 4; ++j) acc[i][j] = 0.f;

        for (int kc = 0; kc < 8; ++kc) {
            const int kb = kc * 64;
            #pragma unroll
            for (int l = 0; l < 16; ++l) {
                const int e = l * 256 + tid;
                const int row = e >> 6, k = e & 63;
                sm.s.aT[k][row] = a[(size_t)(rb * 64 + row) * D + kb + k];
                const int gcol = colbase + row;
                sm.s.tT[k][row] = (gcol < T_ROWS) ? t[(size_t)gcol * D + kb + k] : 0.f;
            }
            __syncthreads();
            #pragma unroll 16
            for (int k = 0; k < 64; ++k) {
                const float4 av4 = *(const float4*)&sm.s.aT[k][r0];
                const float4 bv4 = *(const float4*)&sm.s.tT[k][c0];
                const float am[4] = {av4.x, av4.y, av4.z, av4.w};
                const float bm[4] = {bv4.x, bv4.y, bv4.z, bv4.w};
                #pragma unroll
                for (int i = 0; i < 4; ++i)
                    #pragma unroll
                    for (int j = 0; j < 4; ++j)
                        acc[i][j] = fmaf(am[i], bm[j], acc[i][j]);
            }
            __syncthreads();
        }
        // epilogue: scale by inv-norm and insert into per-thread top-5
        #pragma unroll
        for (int j = 0; j < 4; ++j) {
            const int gcol = colbase + c0 + j;
            if (gcol >= T_ROWS) continue;
            const float it = invt[gcol];
            #pragma unroll
            for (int i = 0; i < 4; ++i)
                top5_insert(tv[i], tix[i], acc[i][j] * it, gcol);
        }
    }

    // merge across the 16 tx-threads of each row via LDS
    __syncthreads();
    #pragma unroll
    for (int i = 0; i < 4; ++i)
        #pragma unroll
        for (int s = 0; s < 5; ++s) {
            const int o = ((ty * 4 + i) * 16 + tx) * 5 + s;
            sm.m.mv[o] = tv[i][s];
            sm.m.mi[o] = tix[i][s];
        }
    __syncthreads();
    if (tid < 64) {
        const int row = tid;
        float bv[5]; int bix[5];
        #pragma unroll
        for (int s = 0; s < 5; ++s) { bv[s] = -INFINITY; bix[s] = 0; }
        for (int t2 = 0; t2 < 16; ++t2)
            #pragma unroll
            for (int s = 0; s < 5; ++s) {
                const int o = (row * 16 + t2) * 5 + s;
                top5_insert(bv, bix, sm.m.mv[o], sm.m.mi[o]);
            }
        const int grow = rb * 64 + row;
        #pragma unroll
        for (int s = 0; s < 5; ++s) {
            cand_val[((size_t)grow * NCC + cc) * 5 + s] = bv[s];
            cand_idx[((size_t)grow * NCC + cc) * 5 + s] = bix[s];
        }
    }
}

// ---------------- Kernel D: merge per-chunk candidates -> top-5 indices per row
__global__ __launch_bounds__(256) void merge_chunks_kernel(const float* __restrict__ cand_val,
                                                           const int* __restrict__ cand_idx,
                                                           int* __restrict__ topk) {
    const int row = blockIdx.x * 256 + threadIdx.x;
    if (row >= W_GRP) return;
    float v[5]; int ix[5];
    #pragma unroll
    for (int s = 0; s < 5; ++s) { v[s] = -INFINITY; ix[s] = 0; }
    for (int c = 0; c < NCC * 5; ++c)
        top5_insert(v, ix, cand_val[(size_t)row * NCC * 5 + c],
                    cand_idx[(size_t)row * NCC * 5 + c]);
    #pragma unroll
    for (int s = 0; s < 5; ++s) topk[row * 5 + s] = ix[s];
}

// ---------------- Kernel E: gather top-5, average, out = avg @ W^T + b
#define RPB 8
__global__ __launch_bounds__(256) void out_kernel(const float* __restrict__ st,
                                                  const float* __restrict__ W,
                                                  const float* __restrict__ b,
                                                  const int* __restrict__ topk,
                                                  float* __restrict__ out) {
    __shared__ float avgT[D][12];   // [i][r], pad to 12 for alignment
    const int tid = threadIdx.x;
    const int rb = blockIdx.x;
    for (int r = 0; r < RPB; ++r) {
        const int grow = rb * RPB + r;
        const int* id = &topk[grow * 5];
        const int i0 = id[0], i1 = id[1], i2 = id[2], i3 = id[3], i4 = id[4];
        #pragma unroll
        for (int cw = 0; cw < 2; ++cw) {
            const int c = tid + cw * 256;
            const float s = (st[(size_t)i0 * D + c] + st[(size_t)i1 * D + c] +
                             st[(size_t)i2 * D + c] + st[(size_t)i3 * D + c] +
                             st[(size_t)i4 * D + c]) * 0.2f;
            avgT[c][r] = s;
        }
    }
    __syncthreads();
    const int j0 = tid * 2;
    float acc0[RPB], acc1[RPB];
    #pragma unroll
    for (int r = 0; r < RPB; ++r) { acc0[r] = 0.f; acc1[r] = 0.f; }
    for (int i = 0; i < D; i += 4) {
        const float4 w0 = *(const float4*)&W[(size_t)j0 * D + i];
        const float4 w1 = *(const float4*)&W[(size_t)(j0 + 1) * D + i];
        const float wa[4] = {w0.x, w0.y, w0.z, w0.w};
        const float wb[4] = {w1.x, w1.y, w1.z, w1.w};
        #pragma unroll
        for (int d = 0; d < 4; ++d) {
            #pragma unroll
            for (int r = 0; r < RPB; ++r) {
                const float av = avgT[i + d][r];
                acc0[r] = fmaf(av, wa[d], acc0[r]);
                acc1[r] = fmaf(av, wb[d], acc1[r]);
            }
        }
    }
    const float b0 = b[j0], b1 = b[j0 + 1];
    #pragma unroll
    for (int r = 0; r < RPB; ++r) {
        const int grow = rb * RPB + r;
        float2 o; o.x = acc0[r] + b0; o.y = acc1[r] + b1;
        *(float2*)&out[(size_t)grow * D + j0] = o;
    }
}

extern "C" void kernel_launch(void* const* d_in, const int* in_sizes, int n_in,
                              void* d_out, int out_size, void* d_ws, size_t ws_size,
                              hipStream_t stream) {
    const float* x  = (const float*)d_in[0];   // (1, 131072, 512)
    const float* st = (const float*)d_in[1];   // (30000, 512)
    const float* W  = (const float*)d_in[2];   // (512, 512)
    const float* b  = (const float*)d_in[3];   // (512,)
    float* out = (float*)d_out;                // (1536, 512)
    float* ws  = (float*)d_ws;

    float* a    = ws;                          // 786432 floats
    float* invt = ws + 786432;                 // 30000 (padded to 32768)
    float* cval = ws + 819200;                 // 1536*30*5 = 230400
    int*   cidx = (int*)(ws + 1049600);        // 230400
    int*   topk = (int*)(ws + 1280000);        // 7680

    avg_norm_kernel<<<W_GRP, 256, 0, stream>>>(x, a);
    tnorm_kernel<<<T_ROWS / 4, 256, 0, stream>>>(st, invt);
    dim3 gC(NCC, NRB);
    score_topk_kernel<<<gC, 256, 0, stream>>>(a, st, invt, cval, cidx);
    merge_chunks_kernel<<<(W_GRP + 255) / 256, 256, 0, stream>>>(cval, cidx, topk);
    out_kernel<<<W_GRP / RPB, 256, 0, stream>>>(st, W, b, topk, out);
}

// Round 2
// 1588.741 us; speedup vs baseline: 1.8231x; 1.8231x over previous
//
#include <hip/hip_runtime.h>
#include <math.h>

#define D 512
#define W_GRP 1536
#define T_ROWS 30000
#define T_PAD 30720
#define NCC 30        // 30 chunks of 1024 cols
#define NRB 24        // 1536/64

typedef unsigned short ushort_t;
typedef short v8s __attribute__((ext_vector_type(8)));
typedef float v4f __attribute__((ext_vector_type(4)));

__device__ __forceinline__ ushort_t rne_bf16(float x) {
    unsigned int u = __float_as_uint(x);
    u = (u + 0x7fffu + ((u >> 16) & 1u)) >> 16;
    return (ushort_t)u;
}
__device__ __forceinline__ float bf16_to_f(ushort_t h) {
    return __uint_as_float(((unsigned int)h) << 16);
}

__device__ __forceinline__ void top5_insert(float (&v)[5], int (&ix)[5], float s, int gi) {
    if (s <= v[4]) return;
    v[4] = s; ix[4] = gi;
    #pragma unroll
    for (int q = 4; q > 0; --q) {
        if (v[q] > v[q-1]) {
            float tv = v[q]; v[q] = v[q-1]; v[q-1] = tv;
            int ti = ix[q]; ix[q] = ix[q-1]; ix[q-1] = ti;
        } else break;
    }
}

// ---------------- Kernel A: group-average + L2-normalize -> a_hi/a_lo bf16 [1536][512]
__global__ __launch_bounds__(256) void avg_norm_kernel(const float* __restrict__ x,
                                                       ushort_t* __restrict__ ah,
                                                       ushort_t* __restrict__ al) {
    const int g = blockIdx.x, tid = threadIdx.x;
    const float* base = x + (size_t)g * 64 * D;
    float s0 = 0.f, s1 = 0.f;
    for (int r = 0; r < 64; ++r) {
        s0 += base[r * D + tid];
        s1 += base[r * D + tid + 256];
    }
    s0 *= (1.f / 64.f); s1 *= (1.f / 64.f);
    float ss = s0 * s0 + s1 * s1;
    for (int off = 32; off > 0; off >>= 1) ss += __shfl_down(ss, off, 64);
    __shared__ float red[4];
    __shared__ float scale_s;
    const int lane = tid & 63, wid = tid >> 6;
    if (lane == 0) red[wid] = ss;
    __syncthreads();
    if (tid == 0) {
        float tot = red[0] + red[1] + red[2] + red[3];
        scale_s = 1.f / fmaxf(sqrtf(tot), 1e-8f);
    }
    __syncthreads();
    const float sc = scale_s;
    const float v0 = s0 * sc, v1 = s1 * sc;
    const ushort_t h0 = rne_bf16(v0), h1 = rne_bf16(v1);
    ah[(size_t)g * D + tid]       = h0;
    ah[(size_t)g * D + tid + 256] = h1;
    al[(size_t)g * D + tid]       = rne_bf16(v0 - bf16_to_f(h0));
    al[(size_t)g * D + tid + 256] = rne_bf16(v1 - bf16_to_f(h1));
}

// ---------------- Kernel B: t -> hi/lo bf16 + inverse row norms
__global__ __launch_bounds__(256) void tconv_kernel(const float* __restrict__ t,
                                                    ushort_t* __restrict__ th,
                                                    ushort_t* __restrict__ tl,
                                                    float* __restrict__ invt) {
    const int wid = threadIdx.x >> 6, lane = threadIdx.x & 63;
    const int row = blockIdx.x * 4 + wid;
    if (row >= T_ROWS) return;
    const float* p = t + (size_t)row * D;
    ushort_t* ph = th + (size_t)row * D;
    ushort_t* pl = tl + (size_t)row * D;
    float ss = 0.f;
    #pragma unroll
    for (int m = 0; m < 8; ++m) {
        const int c = lane + m * 64;
        const float v = p[c];
        ss += v * v;
        const ushort_t h = rne_bf16(v);
        ph[c] = h;
        pl[c] = rne_bf16(v - bf16_to_f(h));
    }
    for (int off = 32; off > 0; off >>= 1) ss += __shfl_down(ss, off, 64);
    if (lane == 0) invt[row] = 1.f / fmaxf(sqrtf(ss), 1e-8f);
}

// ---------------- Kernel C: MFMA scores + fused top-5
// block = 4 waves; wave w covers rows rb*64 + w*16 .. +16, 128 cols per tile, 8 tiles.
__global__ __launch_bounds__(256, 2) void score_topk_kernel(
        const ushort_t* __restrict__ ah, const ushort_t* __restrict__ al,
        const ushort_t* __restrict__ th, const ushort_t* __restrict__ tl,
        const float* __restrict__ invt,
        float* __restrict__ cand_val, int* __restrict__ cand_idx) {
    __shared__ float smv[64 * 16 * 5];
    __shared__ int   smi[64 * 16 * 5];
    const int tid = threadIdx.x;
    const int w = tid >> 6, lane = tid & 63;
    const int quad = lane >> 4, nid = lane & 15;
    const int cc = blockIdx.x, rb = blockIdx.y;
    const int arow = rb * 64 + w * 16 + nid;
    const ushort_t* aph = ah + (size_t)arow * D;
    const ushort_t* apl = al + (size_t)arow * D;
    const int ccbase = cc * 1024;

    float tv[4][5]; int tix[4][5];
    #pragma unroll
    for (int r = 0; r < 4; ++r)
        #pragma unroll
        for (int s = 0; s < 5; ++s) { tv[r][s] = -INFINITY; tix[r][s] = 0; }

    for (int ct = 0; ct < 8; ++ct) {
        const int colbase = ccbase + ct * 128;
        if (colbase >= T_ROWS) break;   // block-uniform
        v4f acc[8];
        #pragma unroll
        for (int cb = 0; cb < 8; ++cb) acc[cb] = (v4f){0.f, 0.f, 0.f, 0.f};

        for (int kt = 0; kt < 16; ++kt) {
            const int koff = kt * 32 + quad * 8;
            const v8s fah = *(const v8s*)(aph + koff);
            const v8s fal = *(const v8s*)(apl + koff);
            v8s bh[8], bl[8];
            #pragma unroll
            for (int cb = 0; cb < 8; ++cb) {
                const size_t tb = (size_t)(colbase + cb * 16 + nid) * D + koff;
                bh[cb] = *(const v8s*)(th + tb);
                bl[cb] = *(const v8s*)(tl + tb);
            }
            #pragma unroll
            for (int cb = 0; cb < 8; ++cb) {
                acc[cb] = __builtin_amdgcn_mfma_f32_16x16x32_bf16(fah, bh[cb], acc[cb], 0, 0, 0);
                acc[cb] = __builtin_amdgcn_mfma_f32_16x16x32_bf16(fal, bh[cb], acc[cb], 0, 0, 0);
                acc[cb] = __builtin_amdgcn_mfma_f32_16x16x32_bf16(fah, bl[cb], acc[cb], 0, 0, 0);
            }
        }
        // epilogue: scale by inv-norm, insert into per-lane top-5
        // C layout (16x16x32): row = quad*4 + r, col = nid  [m89-verified]
        #pragma unroll
        for (int cb = 0; cb < 8; ++cb) {
            const int gcol = colbase + cb * 16 + nid;
            const bool ok = gcol < T_ROWS;
            const float it = ok ? invt[gcol] : 0.f;
            #pragma unroll
            for (int r = 0; r < 4; ++r) {
                const float s = ok ? acc[cb][r] * it : -INFINITY;
                top5_insert(tv[r], tix[r], s, gcol);
            }
        }
    }

    // merge across the 16 lanes (nid) sharing each row
    #pragma unroll
    for (int r = 0; r < 4; ++r) {
        const int row_local = w * 16 + quad * 4 + r;
        #pragma unroll
        for (int s = 0; s < 5; ++s) {
            const int o = (row_local * 16 + nid) * 5 + s;
            smv[o] = tv[r][s];
            smi[o] = tix[r][s];
        }
    }
    __syncthreads();
    if (tid < 64) {
        const int row = tid;
        float bv[5]; int bix[5];
        #pragma unroll
        for (int s = 0; s < 5; ++s) { bv[s] = -INFINITY; bix[s] = 0; }
        for (int t2 = 0; t2 < 16; ++t2)
            #pragma unroll
            for (int s = 0; s < 5; ++s) {
                const int o = (row * 16 + t2) * 5 + s;
                top5_insert(bv, bix, smv[o], smi[o]);
            }
        const int grow = rb * 64 + row;
        #pragma unroll
        for (int s = 0; s < 5; ++s) {
            cand_val[((size_t)grow * NCC + cc) * 5 + s] = bv[s];
            cand_idx[((size_t)grow * NCC + cc) * 5 + s] = bix[s];
        }
    }
}

// ---------------- Kernel D: merge per-chunk candidates -> top-5 indices per row
__global__ __launch_bounds__(256) void merge_chunks_kernel(const float* __restrict__ cand_val,
                                                           const int* __restrict__ cand_idx,
                                                           int* __restrict__ topk) {
    const int row = blockIdx.x * 256 + threadIdx.x;
    if (row >= W_GRP) return;
    float v[5]; int ix[5];
    #pragma unroll
    for (int s = 0; s < 5; ++s) { v[s] = -INFINITY; ix[s] = 0; }
    for (int c = 0; c < NCC * 5; ++c)
        top5_insert(v, ix, cand_val[(size_t)row * NCC * 5 + c],
                    cand_idx[(size_t)row * NCC * 5 + c]);
    #pragma unroll
    for (int s = 0; s < 5; ++s) topk[row * 5 + s] = ix[s];
}

// ---------------- Kernel E: gather top-5, average, out = avg @ W^T + b
#define RPB 8
__global__ __launch_bounds__(256) void out_kernel(const float* __restrict__ st,
                                                  const float* __restrict__ W,
                                                  const float* __restrict__ b,
                                                  const int* __restrict__ topk,
                                                  float* __restrict__ out) {
    __shared__ float avgT[D][12];
    const int tid = threadIdx.x;
    const int rb = blockIdx.x;
    for (int r = 0; r < RPB; ++r) {
        const int grow = rb * RPB + r;
        const int* id = &topk[grow * 5];
        const int i0 = id[0], i1 = id[1], i2 = id[2], i3 = id[3], i4 = id[4];
        #pragma unroll
        for (int cw = 0; cw < 2; ++cw) {
            const int c = tid + cw * 256;
            const float s = (st[(size_t)i0 * D + c] + st[(size_t)i1 * D + c] +
                             st[(size_t)i2 * D + c] + st[(size_t)i3 * D + c] +
                             st[(size_t)i4 * D + c]) * 0.2f;
            avgT[c][r] = s;
        }
    }
    __syncthreads();
    const int j0 = tid * 2;
    float acc0[RPB], acc1[RPB];
    #pragma unroll
    for (int r = 0; r < RPB; ++r) { acc0[r] = 0.f; acc1[r] = 0.f; }
    for (int i = 0; i < D; i += 4) {
        const float4 w0 = *(const float4*)&W[(size_t)j0 * D + i];
        const float4 w1 = *(const float4*)&W[(size_t)(j0 + 1) * D + i];
        const float wa[4] = {w0.x, w0.y, w0.z, w0.w};
        const float wb[4] = {w1.x, w1.y, w1.z, w1.w};
        #pragma unroll
        for (int d = 0; d < 4; ++d) {
            #pragma unroll
            for (int r = 0; r < RPB; ++r) {
                const float av = avgT[i + d][r];
                acc0[r] = fmaf(av, wa[d], acc0[r]);
                acc1[r] = fmaf(av, wb[d], acc1[r]);
            }
        }
    }
    const float b0 = b[j0], b1 = b[j0 + 1];
    #pragma unroll
    for (int r = 0; r < RPB; ++r) {
        const int grow = rb * RPB + r;
        float2 o; o.x = acc0[r] + b0; o.y = acc1[r] + b1;
        *(float2*)&out[(size_t)grow * D + j0] = o;
    }
}

extern "C" void kernel_launch(void* const* d_in, const int* in_sizes, int n_in,
                              void* d_out, int out_size, void* d_ws, size_t ws_size,
                              hipStream_t stream) {
    const float* x  = (const float*)d_in[0];   // (1, 131072, 512)
    const float* st = (const float*)d_in[1];   // (30000, 512)
    const float* W  = (const float*)d_in[2];   // (512, 512)
    const float* b  = (const float*)d_in[3];   // (512,)
    float* out = (float*)d_out;                // (1536, 512)
    char* base = (char*)d_ws;

    ushort_t* th  = (ushort_t*)(base);                 // 30720*512*2 = 31,457,280 B
    ushort_t* tl  = (ushort_t*)(base + 31457280);      // 31,457,280 B
    ushort_t* ah  = (ushort_t*)(base + 62914560);      // 1536*512*2 = 1,572,864 B
    ushort_t* al  = (ushort_t*)(base + 64487424);      // 1,572,864 B
    float*    invt= (float*)   (base + 66060288);      // 131,072 B (30000 used)
    float*    cval= (float*)   (base + 66191360);      // 1536*30*5*4 = 921,600 B
    int*      cidx= (int*)     (base + 67112960);      // 921,600 B
    int*      topk= (int*)     (base + 68034560);      // 30,720 B  -> total ~68.1 MB

    avg_norm_kernel<<<W_GRP, 256, 0, stream>>>(x, ah, al);
    tconv_kernel<<<T_ROWS / 4, 256, 0, stream>>>(st, th, tl, invt);
    dim3 gC(NCC, NRB);
    score_topk_kernel<<<gC, 256, 0, stream>>>(ah, al, th, tl, invt, cval, cidx);
    merge_chunks_kernel<<<(W_GRP + 255) / 256, 256, 0, stream>>>(cval, cidx, topk);
    out_kernel<<<W_GRP / RPB, 256, 0, stream>>>(st, W, b, topk, out);
}

// Round 3
// 1063.230 us; speedup vs baseline: 2.7242x; 1.4943x over previous
//
#include <hip/hip_runtime.h>
#include <math.h>

#define D 512
#define W_GRP 1536
#define T_ROWS 30000
#define T_PAD 30720
#define NCH 240      // col-chunks of 128 (2 tiles of 64 per block)
#define NRB 6        // row-blocks of 256

typedef unsigned short ushort_t;
typedef short v8s __attribute__((ext_vector_type(8)));
typedef float v4f __attribute__((ext_vector_type(4)));

__device__ __forceinline__ ushort_t rne_bf16(float x) {
    unsigned int u = __float_as_uint(x);
    u = (u + 0x7fffu + ((u >> 16) & 1u)) >> 16;
    return (ushort_t)u;
}
__device__ __forceinline__ float bf16_to_f(ushort_t h) {
    return __uint_as_float(((unsigned int)h) << 16);
}

__device__ __forceinline__ void top5_insert(float (&v)[5], int (&ix)[5], float s, int gi) {
    if (s <= v[4]) return;
    v[4] = s; ix[4] = gi;
    #pragma unroll
    for (int q = 4; q > 0; --q) {
        if (v[q] > v[q-1]) {
            float tv = v[q]; v[q] = v[q-1]; v[q-1] = tv;
            int ti = ix[q]; ix[q] = ix[q-1]; ix[q-1] = ti;
        } else break;
    }
}

// ---------------- Kernel A: group-average + L2-normalize -> a_hi/a_lo bf16
// float2 loads; per-column sums bit-identical to the verified scalar version.
__global__ __launch_bounds__(256) void avg_norm_kernel(const float* __restrict__ x,
                                                       ushort_t* __restrict__ ah,
                                                       ushort_t* __restrict__ al) {
    const int g = blockIdx.x, tid = threadIdx.x;
    const float* base = x + (size_t)g * 64 * D + tid * 2;
    float s0 = 0.f, s1 = 0.f;
    #pragma unroll 8
    for (int r = 0; r < 64; ++r) {
        const float2 v = *(const float2*)(base + (size_t)r * D);
        s0 += v.x; s1 += v.y;
    }
    s0 *= (1.f / 64.f); s1 *= (1.f / 64.f);
    float ss = s0 * s0 + s1 * s1;
    for (int off = 32; off > 0; off >>= 1) ss += __shfl_down(ss, off, 64);
    __shared__ float red[4];
    __shared__ float scale_s;
    const int lane = tid & 63, wid = tid >> 6;
    if (lane == 0) red[wid] = ss;
    __syncthreads();
    if (tid == 0) {
        float tot = red[0] + red[1] + red[2] + red[3];
        scale_s = 1.f / fmaxf(sqrtf(tot), 1e-8f);
    }
    __syncthreads();
    const float sc = scale_s;
    const float v0 = s0 * sc, v1 = s1 * sc;
    const ushort_t h0 = rne_bf16(v0), h1 = rne_bf16(v1);
    const ushort_t l0 = rne_bf16(v0 - bf16_to_f(h0));
    const ushort_t l1 = rne_bf16(v1 - bf16_to_f(h1));
    *(unsigned int*)(ah + (size_t)g * D + tid * 2) = (unsigned int)h0 | ((unsigned int)h1 << 16);
    *(unsigned int*)(al + (size_t)g * D + tid * 2) = (unsigned int)l0 | ((unsigned int)l1 << 16);
}

// ---------------- Kernel B: t -> hi/lo bf16 + inverse row norms (float4 loads)
__global__ __launch_bounds__(256) void tconv_kernel(const float* __restrict__ t,
                                                    ushort_t* __restrict__ th,
                                                    ushort_t* __restrict__ tl,
                                                    float* __restrict__ invt) {
    const int wid = threadIdx.x >> 6, lane = threadIdx.x & 63;
    const int row = blockIdx.x * 4 + wid;
    if (row >= T_ROWS) return;
    const float* p = t + (size_t)row * D;
    float ss = 0.f;
    #pragma unroll
    for (int m = 0; m < 2; ++m) {
        const int c = lane * 4 + m * 256;
        const float4 v = *(const float4*)(p + c);
        ss += v.x * v.x + v.y * v.y + v.z * v.z + v.w * v.w;
        const ushort_t h0 = rne_bf16(v.x), h1 = rne_bf16(v.y), h2 = rne_bf16(v.z), h3 = rne_bf16(v.w);
        const ushort_t l0 = rne_bf16(v.x - bf16_to_f(h0));
        const ushort_t l1 = rne_bf16(v.y - bf16_to_f(h1));
        const ushort_t l2 = rne_bf16(v.z - bf16_to_f(h2));
        const ushort_t l3 = rne_bf16(v.w - bf16_to_f(h3));
        uint2 hp, lp;
        hp.x = (unsigned int)h0 | ((unsigned int)h1 << 16);
        hp.y = (unsigned int)h2 | ((unsigned int)h3 << 16);
        lp.x = (unsigned int)l0 | ((unsigned int)l1 << 16);
        lp.y = (unsigned int)l2 | ((unsigned int)l3 << 16);
        *(uint2*)(th + (size_t)row * D + c) = hp;
        *(uint2*)(tl + (size_t)row * D + c) = lp;
    }
    for (int off = 32; off > 0; off >>= 1) ss += __shfl_down(ss, off, 64);
    if (lane == 0) invt[row] = 1.f / fmaxf(sqrtf(ss), 1e-8f);
}

// ---------------- Kernel C: MFMA scores, LDS-staged B, fused top-5
// Block: 4 waves x 64 rows = 256 rows; 2 col-tiles of 64 (128 cols); grid (240, 6).
// Wave tile 64x64: 4x4 fragments, 3 MFMA terms (hh, lh, hl) per pair.
union SMemC {
    ushort_t stage[2][2][256][8];   // [buf][hi/lo][unit][8 shorts] = 16 KB
    float epi[4][64][33];           // per-wave 64x32(+pad) score slab = 33.8 KB
};

__global__ __launch_bounds__(256) void score_topk_kernel(
        const ushort_t* __restrict__ ah, const ushort_t* __restrict__ al,
        const ushort_t* __restrict__ th, const ushort_t* __restrict__ tl,
        const float* __restrict__ invt,
        float* __restrict__ cand_val, int* __restrict__ cand_idx) {
    __shared__ SMemC sm;
    const int tid = threadIdx.x;
    const int w = tid >> 6, lane = tid & 63;
    const int quad = lane >> 4, nid = lane & 15;
    const int cc = blockIdx.x, rb = blockIdx.y;
    const int wrow0 = rb * 256 + w * 64;

    // A fragment base pointers (hi/lo), fixed rows per wave
    const ushort_t* aph[4];
    const ushort_t* apl[4];
    #pragma unroll
    for (int fi = 0; fi < 4; ++fi) {
        const size_t ro = (size_t)(wrow0 + fi * 16 + nid) * D + quad * 8;
        aph[fi] = ah + ro;
        apl[fi] = al + ro;
    }

    // staging map: thread t covers unit t: col = t&63, kseg = t>>6
    const int col_s = tid & 63, seg_s = tid >> 6;

    float tv[5]; int tix[5];
    #pragma unroll
    for (int s = 0; s < 5; ++s) { tv[s] = -INFINITY; tix[s] = 0; }

    for (int ct = 0; ct < 2; ++ct) {
        const int cb64 = cc * 128 + ct * 64;
        const ushort_t* gth = th + (size_t)(cb64 + col_s) * D + seg_s * 8;
        const ushort_t* gtl = tl + (size_t)(cb64 + col_s) * D + seg_s * 8;

        v4f acc[4][4];
        #pragma unroll
        for (int fi = 0; fi < 4; ++fi)
            #pragma unroll
            for (int fj = 0; fj < 4; ++fj) acc[fi][fj] = (v4f){0.f, 0.f, 0.f, 0.f};

        // prologue: stage kt=0 into buf 0
        {
            const v8s h0 = *(const v8s*)gth;
            const v8s l0 = *(const v8s*)gtl;
            *(v8s*)&sm.stage[0][0][tid][0] = h0;
            *(v8s*)&sm.stage[0][1][tid][0] = l0;
        }
        __syncthreads();

        for (int kt = 0; kt < 16; ++kt) {
            const int kb = kt * 32;
            const int cur = kt & 1, nxt = cur ^ 1;
            v8s nh, nl;
            if (kt < 15) {             // prefetch next k-slab into registers
                nh = *(const v8s*)(gth + kb + 32);
                nl = *(const v8s*)(gtl + kb + 32);
            }
            v8s fah[4], fal[4];
            #pragma unroll
            for (int fi = 0; fi < 4; ++fi) {
                fah[fi] = *(const v8s*)(aph[fi] + kb);
                fal[fi] = *(const v8s*)(apl[fi] + kb);
            }
            #pragma unroll
            for (int fj = 0; fj < 4; ++fj) {
                const int u = quad * 64 + fj * 16 + nid;
                const v8s bh = *(const v8s*)&sm.stage[cur][0][u][0];
                const v8s bl = *(const v8s*)&sm.stage[cur][1][u][0];
                #pragma unroll
                for (int fi = 0; fi < 4; ++fi) {
                    acc[fi][fj] = __builtin_amdgcn_mfma_f32_16x16x32_bf16(fah[fi], bh, acc[fi][fj], 0, 0, 0);
                    acc[fi][fj] = __builtin_amdgcn_mfma_f32_16x16x32_bf16(fal[fi], bh, acc[fi][fj], 0, 0, 0);
                    acc[fi][fj] = __builtin_amdgcn_mfma_f32_16x16x32_bf16(fah[fi], bl, acc[fi][fj], 0, 0, 0);
                }
            }
            if (kt < 15) {
                *(v8s*)&sm.stage[nxt][0][tid][0] = nh;
                *(v8s*)&sm.stage[nxt][1][tid][0] = nl;
            }
            __syncthreads();
        }

        // epilogue: two 32-col passes through LDS; lane l owns local row l
        #pragma unroll
        for (int h = 0; h < 2; ++h) {
            #pragma unroll
            for (int fjh = 0; fjh < 2; ++fjh) {
                const int fj = h * 2 + fjh;
                const int gcol = cb64 + fj * 16 + nid;
                const bool ok = gcol < T_ROWS;
                const float it = ok ? invt[gcol] : 0.f;
                #pragma unroll
                for (int fi = 0; fi < 4; ++fi)
                    #pragma unroll
                    for (int r = 0; r < 4; ++r) {
                        const int row = fi * 16 + quad * 4 + r;
                        sm.epi[w][row][fjh * 16 + nid] = ok ? acc[fi][fj][r] * it : -INFINITY;
                    }
            }
            __syncthreads();
            #pragma unroll 8
            for (int c = 0; c < 32; ++c)
                top5_insert(tv, tix, sm.epi[w][lane][c], cb64 + h * 32 + c);
            __syncthreads();
        }
    }

    // write per-row top-5 for this 128-col chunk
    const int grow = rb * 256 + tid;          // w*64 + lane == tid
    #pragma unroll
    for (int s = 0; s < 5; ++s) {
        cand_val[((size_t)grow * NCH + cc) * 5 + s] = tv[s];
        cand_idx[((size_t)grow * NCH + cc) * 5 + s] = tix[s];
    }
}

// ---------------- Kernel D: merge per-chunk candidates -> top-5 indices per row
__global__ __launch_bounds__(256) void merge_chunks_kernel(const float* __restrict__ cand_val,
                                                           const int* __restrict__ cand_idx,
                                                           int* __restrict__ topk) {
    const int row = blockIdx.x * 256 + threadIdx.x;
    if (row >= W_GRP) return;
    float v[5]; int ix[5];
    #pragma unroll
    for (int s = 0; s < 5; ++s) { v[s] = -INFINITY; ix[s] = 0; }
    for (int c = 0; c < NCH * 5; ++c)
        top5_insert(v, ix, cand_val[(size_t)row * NCH * 5 + c],
                    cand_idx[(size_t)row * NCH * 5 + c]);
    #pragma unroll
    for (int s = 0; s < 5; ++s) topk[row * 5 + s] = ix[s];
}

// ---------------- Kernel E: gather top-5, average, out = avg @ W^T + b
#define RPB 8
__global__ __launch_bounds__(256) void out_kernel(const float* __restrict__ st,
                                                  const float* __restrict__ W,
                                                  const float* __restrict__ b,
                                                  const int* __restrict__ topk,
                                                  float* __restrict__ out) {
    __shared__ float avgT[D][12];
    const int tid = threadIdx.x;
    const int rb = blockIdx.x;
    for (int r = 0; r < RPB; ++r) {
        const int grow = rb * RPB + r;
        const int* id = &topk[grow * 5];
        const int i0 = id[0], i1 = id[1], i2 = id[2], i3 = id[3], i4 = id[4];
        #pragma unroll
        for (int cw = 0; cw < 2; ++cw) {
            const int c = tid + cw * 256;
            const float s = (st[(size_t)i0 * D + c] + st[(size_t)i1 * D + c] +
                             st[(size_t)i2 * D + c] + st[(size_t)i3 * D + c] +
                             st[(size_t)i4 * D + c]) * 0.2f;
            avgT[c][r] = s;
        }
    }
    __syncthreads();
    const int j0 = tid * 2;
    float acc0[RPB], acc1[RPB];
    #pragma unroll
    for (int r = 0; r < RPB; ++r) { acc0[r] = 0.f; acc1[r] = 0.f; }
    for (int i = 0; i < D; i += 4) {
        const float4 w0 = *(const float4*)&W[(size_t)j0 * D + i];
        const float4 w1 = *(const float4*)&W[(size_t)(j0 + 1) * D + i];
        const float wa[4] = {w0.x, w0.y, w0.z, w0.w};
        const float wb[4] = {w1.x, w1.y, w1.z, w1.w};
        #pragma unroll
        for (int d = 0; d < 4; ++d) {
            #pragma unroll
            for (int r = 0; r < RPB; ++r) {
                const float av = avgT[i + d][r];
                acc0[r] = fmaf(av, wa[d], acc0[r]);
                acc1[r] = fmaf(av, wb[d], acc1[r]);
            }
        }
    }
    const float b0 = b[j0], b1 = b[j0 + 1];
    #pragma unroll
    for (int r = 0; r < RPB; ++r) {
        const int grow = rb * RPB + r;
        float2 o; o.x = acc0[r] + b0; o.y = acc1[r] + b1;
        *(float2*)&out[(size_t)grow * D + j0] = o;
    }
}

extern "C" void kernel_launch(void* const* d_in, const int* in_sizes, int n_in,
                              void* d_out, int out_size, void* d_ws, size_t ws_size,
                              hipStream_t stream) {
    const float* x  = (const float*)d_in[0];   // (1, 131072, 512)
    const float* st = (const float*)d_in[1];   // (30000, 512)
    const float* W  = (const float*)d_in[2];   // (512, 512)
    const float* b  = (const float*)d_in[3];   // (512,)
    float* out = (float*)d_out;                // (1536, 512)
    char* base = (char*)d_ws;

    ushort_t* th  = (ushort_t*)(base);                 // 30720*512*2 = 31,457,280 B
    ushort_t* tl  = (ushort_t*)(base + 31457280);      // 31,457,280 B
    ushort_t* ah  = (ushort_t*)(base + 62914560);      // 1,572,864 B
    ushort_t* al  = (ushort_t*)(base + 64487424);      // 1,572,864 B
    float*    invt= (float*)   (base + 66060288);      // 131,072 B
    float*    cval= (float*)   (base + 66191360);      // 1536*240*5*4 = 7,372,800 B
    int*      cidx= (int*)     (base + 73564160);      // 7,372,800 B
    int*      topk= (int*)     (base + 80936960);      // 30,720 B -> total ~81 MB

    avg_norm_kernel<<<W_GRP, 256, 0, stream>>>(x, ah, al);
    tconv_kernel<<<(T_ROWS + 3) / 4, 256, 0, stream>>>(st, th, tl, invt);
    dim3 gC(NCH, NRB);
    score_topk_kernel<<<gC, 256, 0, stream>>>(ah, al, th, tl, invt, cval, cidx);
    merge_chunks_kernel<<<(W_GRP + 255) / 256, 256, 0, stream>>>(cval, cidx, topk);
    out_kernel<<<W_GRP / RPB, 256, 0, stream>>>(st, W, b, topk, out);
}